// Round 1
// baseline (302.241 us; speedup 1.0000x reference)
//
#include <hip/hip_runtime.h>

// out[b,h,w,c] = sum_j w[j,c] * t_j[b,h,w,c]
// B,H,W,C = 8,128,128,128 -> N = 16,777,216 f32 elements.
// Pure HBM-bound elementwise op: 5 reads + 1 write = 384 MiB/call.
// float4 vectorized; C=128 innermost so each float4 = 4 consecutive channels
// and (idx & 31)*4 gives the channel base, invariant per thread.

__global__ __launch_bounds__(256) void merge5_kernel(
    const float* __restrict__ t1, const float* __restrict__ t2,
    const float* __restrict__ t3, const float* __restrict__ t4,
    const float* __restrict__ t5, const float* __restrict__ w,
    float* __restrict__ out, int nvec)
{
    int idx = blockIdx.x * 256 + threadIdx.x;
    if (idx >= nvec) return;

    // channel base for this float4 (C=128 -> 32 float4s per channel period)
    int c4 = (idx & 31) << 2;

    const float4 w0 = *(const float4*)(w + 0 * 128 + c4);
    const float4 w1 = *(const float4*)(w + 1 * 128 + c4);
    const float4 w2 = *(const float4*)(w + 2 * 128 + c4);
    const float4 w3 = *(const float4*)(w + 3 * 128 + c4);
    const float4 w4 = *(const float4*)(w + 4 * 128 + c4);

    float4 a = ((const float4*)t1)[idx];
    float4 b = ((const float4*)t2)[idx];
    float4 c = ((const float4*)t3)[idx];
    float4 d = ((const float4*)t4)[idx];
    float4 e = ((const float4*)t5)[idx];

    float4 r;
    r.x = a.x * w0.x + b.x * w1.x + c.x * w2.x + d.x * w3.x + e.x * w4.x;
    r.y = a.y * w0.y + b.y * w1.y + c.y * w2.y + d.y * w3.y + e.y * w4.y;
    r.z = a.z * w0.z + b.z * w1.z + c.z * w2.z + d.z * w3.z + e.z * w4.z;
    r.w = a.w * w0.w + b.w * w1.w + c.w * w2.w + d.w * w3.w + e.w * w4.w;

    ((float4*)out)[idx] = r;
}

extern "C" void kernel_launch(void* const* d_in, const int* in_sizes, int n_in,
                              void* d_out, int out_size, void* d_ws, size_t ws_size,
                              hipStream_t stream) {
    const float* t1 = (const float*)d_in[0];
    const float* t2 = (const float*)d_in[1];
    const float* t3 = (const float*)d_in[2];
    const float* t4 = (const float*)d_in[3];
    const float* t5 = (const float*)d_in[4];
    const float* w  = (const float*)d_in[5];
    float* out = (float*)d_out;

    int nvec = out_size / 4;           // 16,777,216 / 4 = 4,194,304 float4s
    int blocks = (nvec + 255) / 256;   // 16384

    merge5_kernel<<<blocks, 256, 0, stream>>>(t1, t2, t3, t4, t5, w, out, nvec);
}